// Round 8
// baseline (429.026 us; speedup 1.0000x reference)
//
#include <hip/hip_runtime.h>
#include <math.h>

#define NPG 1000
#define KTOP 500
#define C 64
#define EPG 16000   // edges per graph = NPG * DEG
#define BPG 63      // gather blocks per graph: ceil(250/4), 4 bases/block, 4 nodes/base-wave

__device__ __forceinline__ int readlane_i(int v, int l) {
    return (int)__builtin_amdgcn_readlane((unsigned)v, (unsigned)l);
}

// ---------------- fused per-graph CSR build: count + scan + scatter in LDS ----------------
// Also zeroes this graph's cen_sum slice (replaces a memset dispatch).
__global__ __launch_bounds__(1024) void build_graph_k(const int* __restrict__ ei, int E,
                                                      int* __restrict__ deg,
                                                      float* __restrict__ dinv,
                                                      int* __restrict__ off,
                                                      int* __restrict__ csr,
                                                      float* __restrict__ cen_sum) {
    int g = blockIdx.x, t = threadIdx.x;
    __shared__ int cnt[NPG];               // counts, then cursors
    __shared__ int soff[NPG];              // local start offsets
    __shared__ unsigned short lcsr[EPG];   // src local ids, dst-grouped
    __shared__ int red[1024];
    const int gbase = g * NPG;
    const int ebase = g * EPG;
    const int* __restrict__ srcp = ei + ebase;
    const int* __restrict__ dstp = ei + E + ebase;

    if (t < C) cen_sum[(size_t)g * C + t] = 0.f;
    for (int i = t; i < NPG; i += 1024) cnt[i] = 0;
    __syncthreads();
    // phase 1: count in-degree (LDS atomics)
    for (int i = t; i < EPG; i += 1024) atomicAdd(&cnt[dstp[i] - gbase], 1);
    __syncthreads();
    // phase 2: exclusive scan over 1000 counts (1/thread, Hillis-Steele on 1024)
    int v = (t < NPG) ? cnt[t] : 0;
    red[t] = v;
    __syncthreads();
    for (int o = 1; o < 1024; o <<= 1) {
        int xx = (t >= o) ? red[t - o] : 0;
        __syncthreads();
        red[t] += xx;
        __syncthreads();
    }
    if (t < NPG) soff[t] = red[t] - v;     // exclusive prefix
    __syncthreads();
    // outputs: deg, dinv, off (coalesced)
    for (int i = t; i < NPG; i += 1024) {
        int d = cnt[i];
        deg[gbase + i] = d;
        dinv[gbase + i] = 1.0f / sqrtf((float)(d + 1));
        off[gbase + i] = ebase + soff[i];
    }
    __syncthreads();
    // reset cursors
    for (int i = t; i < NPG; i += 1024) cnt[i] = soff[i];
    __syncthreads();
    // phase 3: scatter src into dst-grouped order (LDS cursor atomics + LDS writes)
    for (int i = t; i < EPG; i += 1024) {
        int d = dstp[i] - gbase;
        int pos = atomicAdd(&cnt[d], 1);
        lcsr[pos] = (unsigned short)(srcp[i] - gbase);
    }
    __syncthreads();
    // phase 4: dump csr as coalesced int4 stores (EPG % 4 == 0)
    int4* co = (int4*)(csr + ebase);
    for (int i = t; i < EPG / 4; i += 1024) {
        int4 vv;
        vv.x = gbase + (int)lcsr[i * 4 + 0];
        vv.y = gbase + (int)lcsr[i * 4 + 1];
        vv.z = gbase + (int)lcsr[i * 4 + 2];
        vv.w = gbase + (int)lcsr[i * 4 + 3];
        co[i] = vv;
    }
}

// ---------------- h2 = (x @ W) * dinv[row] : tiled GEMM, 8x8 register tile --------------
__global__ __launch_bounds__(128) void gemm_k(const float* __restrict__ x,
                                              const float* __restrict__ W,
                                              const float* __restrict__ dinv,
                                              float* __restrict__ h2, int N) {
    __shared__ float xT[64][132];          // transposed x tile
    __shared__ float sW[C * C];
    int t = threadIdx.x;
    int rbase = blockIdx.x * 128;          // N % 128 == 0
    if (rbase >= N) return;
    for (int i = t; i < C * C / 4; i += 128) ((float4*)sW)[i] = ((const float4*)W)[i];
    const float4* xsrc = (const float4*)(x + (size_t)rbase * C);
    for (int i = t; i < 2048; i += 128) {
        float4 v = xsrc[i];
        int r = i >> 4;
        int k0 = (i & 15) * 4;
        xT[k0 + 0][r] = v.x;
        xT[k0 + 1][r] = v.y;
        xT[k0 + 2][r] = v.z;
        xT[k0 + 3][r] = v.w;
    }
    __syncthreads();
    int rg = t >> 3;
    int cg = t & 7;
    int r0 = rg * 8;
    int c0 = cg * 8;
    float acc[8][8];
#pragma unroll
    for (int i = 0; i < 8; ++i)
#pragma unroll
        for (int j = 0; j < 8; ++j) acc[i][j] = 0.f;
    for (int k = 0; k < 64; ++k) {
        float4 a0 = *(const float4*)&xT[k][r0];
        float4 a1 = *(const float4*)&xT[k][r0 + 4];
        float4 b0 = *(const float4*)&sW[k * C + c0];
        float4 b1 = *(const float4*)&sW[k * C + c0 + 4];
        float av[8] = { a0.x, a0.y, a0.z, a0.w, a1.x, a1.y, a1.z, a1.w };
        float bv[8] = { b0.x, b0.y, b0.z, b0.w, b1.x, b1.y, b1.z, b1.w };
#pragma unroll
        for (int i = 0; i < 8; ++i)
#pragma unroll
            for (int j = 0; j < 8; ++j)
                acc[i][j] = fmaf(av[i], bv[j], acc[i][j]);
    }
    float dv[8];
#pragma unroll
    for (int i = 0; i < 8; ++i) dv[i] = dinv[rbase + r0 + i];
#pragma unroll
    for (int i = 0; i < 8; ++i) {
        float4 o0, o1;
        o0.x = acc[i][0] * dv[i]; o0.y = acc[i][1] * dv[i];
        o0.z = acc[i][2] * dv[i]; o0.w = acc[i][3] * dv[i];
        o1.x = acc[i][4] * dv[i]; o1.y = acc[i][5] * dv[i];
        o1.z = acc[i][6] * dv[i]; o1.w = acc[i][7] * dv[i];
        float4* dst = (float4*)(h2 + (size_t)(rbase + r0 + i) * C + c0);
        dst[0] = o0;
        dst[1] = o1;
    }
}

// ---------------- gather aggregation: float4 rows, 4 nodes per wave ----------------------
// Lane split: q = lane>>4 (edge phase), m = lane&15 (float4 slot of the row).
// Per 4-edge chunk per node: 1 ds_bpermute (neighbor id for edge j+q) + 1 dwordx4 load
// (64 lanes = 4 full rows) + 4 f32 adds. 4x fewer VMEM instructions and address chains
// than the scalar-per-channel scheme at identical bytes. Per-node guarded trip counts;
// pad slots hold own id, compensated via coef fold. Butterfly shfl_xor(16,32) sums the
// 4 q-groups; q==0 lanes store the row as one dwordx4. Centroid fused as before.
__global__ __launch_bounds__(256) void gather_k(const int* __restrict__ csr,
                                                const int* __restrict__ off,
                                                const int* __restrict__ deg,
                                                const float* __restrict__ h2,
                                                const float* __restrict__ dinv,
                                                const float* __restrict__ bias,
                                                float* __restrict__ out2,
                                                float* __restrict__ cen_sum,
                                                int N, int B) {
    __shared__ float cenacc[C];
    int blk = blockIdx.x;
    int wave = threadIdx.x >> 6;
    int lane = threadIdx.x & 63;
    int t = threadIdx.x;
    int q = lane >> 4;
    int m = lane & 15;
    int g, blkin;
    if ((B & 7) == 0) {                    // XCD swizzle: whole graph on one XCD
        int xcd = blk & 7, slot = blk >> 3;
        g = (slot / BPG) * 8 + xcd;
        blkin = slot % BPG;
    } else {
        g = blk / BPG;
        blkin = blk % BPG;
    }
    if (t < C) cenacc[t] = 0.f;
    __syncthreads();

    int base = blkin * 4 + wave;
    if (base < NPG / 4) {
        float4 bv = ((const float4*)bias)[m];
        int nA = g * NPG + base;
        int nB = nA + 250, nC_ = nA + 500, nD = nA + 750;
        int oA = off[nA], oB = off[nB], oC = off[nC_], oD = off[nD];
        int dA = deg[nA], dB = deg[nB], dC = deg[nC_], dD = deg[nD];
        float diA = dinv[nA], diB = dinv[nB], diC = dinv[nC_], diD = dinv[nD];
        float4 hA = ((const float4*)(h2 + (size_t)nA * C))[m];
        float4 hB = ((const float4*)(h2 + (size_t)nB * C))[m];
        float4 hC = ((const float4*)(h2 + (size_t)nC_ * C))[m];
        float4 hD = ((const float4*)(h2 + (size_t)nD * C))[m];
        int svA = (lane < dA) ? csr[oA + lane] : nA;
        int svB = (lane < dB) ? csr[oB + lane] : nB;
        int svC = (lane < dC) ? csr[oC + lane] : nC_;
        int svD = (lane < dD) ? csr[oD + lane] : nD;
        int jmA = dA < 64 ? dA : 64;
        int jmB = dB < 64 ? dB : 64;
        int jmC = dC < 64 ? dC : 64;
        int jmD = dD < 64 ? dD : 64;
        int rA = (jmA + 3) & ~3, rB = (jmB + 3) & ~3;
        int rC = (jmC + 3) & ~3, rD = (jmD + 3) & ~3;
        int m0 = rA > rB ? rA : rB;
        int m1 = rC > rD ? rC : rD;
        int mmax = m0 > m1 ? m0 : m1;
        float4 aA = {0.f,0.f,0.f,0.f}, aB = {0.f,0.f,0.f,0.f};
        float4 aC = {0.f,0.f,0.f,0.f}, aD = {0.f,0.f,0.f,0.f};
        for (int j = 0; j < mmax; j += 4) {
            int bidx = (j + q) << 2;       // byte index for ds_bpermute
            if (j < rA) {
                int s = __builtin_amdgcn_ds_bpermute(bidx, svA);
                float4 v = ((const float4*)(h2 + (size_t)s * C))[m];
                aA.x += v.x; aA.y += v.y; aA.z += v.z; aA.w += v.w;
            }
            if (j < rB) {
                int s = __builtin_amdgcn_ds_bpermute(bidx, svB);
                float4 v = ((const float4*)(h2 + (size_t)s * C))[m];
                aB.x += v.x; aB.y += v.y; aB.z += v.z; aB.w += v.w;
            }
            if (j < rC) {
                int s = __builtin_amdgcn_ds_bpermute(bidx, svC);
                float4 v = ((const float4*)(h2 + (size_t)s * C))[m];
                aC.x += v.x; aC.y += v.y; aC.z += v.z; aC.w += v.w;
            }
            if (j < rD) {
                int s = __builtin_amdgcn_ds_bpermute(bidx, svD);
                float4 v = ((const float4*)(h2 + (size_t)s * C))[m];
                aD.x += v.x; aD.y += v.y; aD.z += v.z; aD.w += v.w;
            }
        }
        // deg > 64 overflow (essentially never: Poisson(16)); count once via q==0
        for (int j = 64; j < dA; ++j) {
            int s = csr[oA + j];
            if (q == 0) { float4 v = ((const float4*)(h2 + (size_t)s * C))[m];
                          aA.x += v.x; aA.y += v.y; aA.z += v.z; aA.w += v.w; }
        }
        for (int j = 64; j < dB; ++j) {
            int s = csr[oB + j];
            if (q == 0) { float4 v = ((const float4*)(h2 + (size_t)s * C))[m];
                          aB.x += v.x; aB.y += v.y; aB.z += v.z; aB.w += v.w; }
        }
        for (int j = 64; j < dC; ++j) {
            int s = csr[oC + j];
            if (q == 0) { float4 v = ((const float4*)(h2 + (size_t)s * C))[m];
                          aC.x += v.x; aC.y += v.y; aC.z += v.z; aC.w += v.w; }
        }
        for (int j = 64; j < dD; ++j) {
            int s = csr[oD + j];
            if (q == 0) { float4 v = ((const float4*)(h2 + (size_t)s * C))[m];
                          aD.x += v.x; aD.y += v.y; aD.z += v.z; aD.w += v.w; }
        }
        // butterfly reduce across the 4 q-groups (lanes m, 16+m, 32+m, 48+m)
        for (int o = 16; o < 64; o <<= 1) {
            aA.x += __shfl_xor(aA.x, o, 64); aA.y += __shfl_xor(aA.y, o, 64);
            aA.z += __shfl_xor(aA.z, o, 64); aA.w += __shfl_xor(aA.w, o, 64);
            aB.x += __shfl_xor(aB.x, o, 64); aB.y += __shfl_xor(aB.y, o, 64);
            aB.z += __shfl_xor(aB.z, o, 64); aB.w += __shfl_xor(aB.w, o, 64);
            aC.x += __shfl_xor(aC.x, o, 64); aC.y += __shfl_xor(aC.y, o, 64);
            aC.z += __shfl_xor(aC.z, o, 64); aC.w += __shfl_xor(aC.w, o, 64);
            aD.x += __shfl_xor(aD.x, o, 64); aD.y += __shfl_xor(aD.y, o, 64);
            aD.z += __shfl_xor(aD.z, o, 64); aD.w += __shfl_xor(aD.w, o, 64);
        }
        // pad compensation: acc holds (rN - jmN) extra copies of own row; want exactly +1
        float cA = 1.0f - (float)(rA - jmA);
        float cB = 1.0f - (float)(rB - jmB);
        float cC = 1.0f - (float)(rC - jmC);
        float cD = 1.0f - (float)(rD - jmD);
        float4 resA, resB, resC, resD;
        resA.x = fmaf(diA, fmaf(cA, hA.x, aA.x), bv.x);
        resA.y = fmaf(diA, fmaf(cA, hA.y, aA.y), bv.y);
        resA.z = fmaf(diA, fmaf(cA, hA.z, aA.z), bv.z);
        resA.w = fmaf(diA, fmaf(cA, hA.w, aA.w), bv.w);
        resB.x = fmaf(diB, fmaf(cB, hB.x, aB.x), bv.x);
        resB.y = fmaf(diB, fmaf(cB, hB.y, aB.y), bv.y);
        resB.z = fmaf(diB, fmaf(cB, hB.z, aB.z), bv.z);
        resB.w = fmaf(diB, fmaf(cB, hB.w, aB.w), bv.w);
        resC.x = fmaf(diC, fmaf(cC, hC.x, aC.x), bv.x);
        resC.y = fmaf(diC, fmaf(cC, hC.y, aC.y), bv.y);
        resC.z = fmaf(diC, fmaf(cC, hC.z, aC.z), bv.z);
        resC.w = fmaf(diC, fmaf(cC, hC.w, aC.w), bv.w);
        resD.x = fmaf(diD, fmaf(cD, hD.x, aD.x), bv.x);
        resD.y = fmaf(diD, fmaf(cD, hD.y, aD.y), bv.y);
        resD.z = fmaf(diD, fmaf(cD, hD.z, aD.z), bv.z);
        resD.w = fmaf(diD, fmaf(cD, hD.w, aD.w), bv.w);
        if (q == 0) {
            ((float4*)(out2 + (size_t)nA * C))[m] = resA;
            ((float4*)(out2 + (size_t)nB * C))[m] = resB;
            ((float4*)(out2 + (size_t)nC_ * C))[m] = resC;
            ((float4*)(out2 + (size_t)nD * C))[m] = resD;
            float sx = (resA.x + resB.x) + (resC.x + resD.x);
            float sy = (resA.y + resB.y) + (resC.y + resD.y);
            float sz = (resA.z + resB.z) + (resC.z + resD.z);
            float sw = (resA.w + resB.w) + (resC.w + resD.w);
            atomicAdd(&cenacc[m * 4 + 0], sx);
            atomicAdd(&cenacc[m * 4 + 1], sy);
            atomicAdd(&cenacc[m * 4 + 2], sz);
            atomicAdd(&cenacc[m * 4 + 3], sw);
        }
    }
    __syncthreads();
    if (t < C) atomicAdd(&cen_sum[(size_t)g * C + t], cenacc[t]);
}

// ---------------- score: device-wide, wave per 4 rows; cen/cnorm derived inline ----------
__global__ __launch_bounds__(256) void score2_k(const float* __restrict__ out2,
                                                const float* __restrict__ cen_sum,
                                                float* __restrict__ score, int N) {
    int wave = threadIdx.x >> 6, lane = threadIdx.x & 63;
    int r0 = blockIdx.x * 16 + wave * 4;          // 4 rows per wave
    if (r0 >= N) return;
    int g0 = (r0 + 0) / NPG, g1 = (r0 + 1) / NPG;
    int g2 = (r0 + 2) / NPG, g3 = (r0 + 3) / NPG;
    const float inv = 1.0f / 1000.0f;
    float m0 = cen_sum[(size_t)g0 * C + lane] * inv;
    float m1 = cen_sum[(size_t)g1 * C + lane] * inv;
    float m2 = cen_sum[(size_t)g2 * C + lane] * inv;
    float m3 = cen_sum[(size_t)g3 * C + lane] * inv;
    float a0 = out2[(size_t)(r0 + 0) * C + lane];
    float a1 = out2[(size_t)(r0 + 1) * C + lane];
    float a2 = out2[(size_t)(r0 + 2) * C + lane];
    float a3 = out2[(size_t)(r0 + 3) * C + lane];
    float n0 = a0 * m0, n1 = a1 * m1, n2 = a2 * m2, n3 = a3 * m3;
    float q0 = a0 * a0, q1 = a1 * a1, q2 = a2 * a2, q3 = a3 * a3;
    float c0 = m0 * m0, c1 = m1 * m1, c2 = m2 * m2, c3 = m3 * m3;
    for (int o = 32; o > 0; o >>= 1) {
        n0 += __shfl_down(n0, o, 64); q0 += __shfl_down(q0, o, 64); c0 += __shfl_down(c0, o, 64);
        n1 += __shfl_down(n1, o, 64); q1 += __shfl_down(q1, o, 64); c1 += __shfl_down(c1, o, 64);
        n2 += __shfl_down(n2, o, 64); q2 += __shfl_down(q2, o, 64); c2 += __shfl_down(c2, o, 64);
        n3 += __shfl_down(n3, o, 64); q3 += __shfl_down(q3, o, 64); c3 += __shfl_down(c3, o, 64);
    }
    if (lane == 0) {
        score[r0 + 0] = n0 / (sqrtf(q0) * sqrtf(c0) + 1e-8f);
        score[r0 + 1] = n1 / (sqrtf(q1) * sqrtf(c1) + 1e-8f);
        score[r0 + 2] = n2 / (sqrtf(q2) * sqrtf(c2) + 1e-8f);
        score[r0 + 3] = n3 / (sqrtf(q3) * sqrtf(c3) + 1e-8f);
    }
}

// ---------------- per-graph tail: softmax-KL + bitonic argsort + top-K + x_new ----------
__global__ __launch_bounds__(1024) void post2_k(const float* __restrict__ score,
                                                const float* __restrict__ out2,
                                                int* __restrict__ mapping,
                                                float* __restrict__ o_xnew,
                                                float* __restrict__ o_batch,
                                                float* __restrict__ o_perm,
                                                float* __restrict__ o_kl,
                                                float* __restrict__ o_ind) {
    __shared__ float ss[NPG];
    __shared__ float red[1024];
    __shared__ unsigned long long kk[1024];
    __shared__ int   map[NPG];
    int g = blockIdx.x, t = threadIdx.x;
    int wave = t >> 6, lane = t & 63;
    const int gbase = g * NPG;

    const float4* s4 = (const float4*)(score + (size_t)gbase);
    if (t < NPG / 4) ((float4*)ss)[t] = s4[t];
    __syncthreads();
    float mx = -INFINITY;
    if (t < NPG) mx = ss[t];
    red[t] = mx;
    __syncthreads();
    for (int w = 512; w > 0; w >>= 1) { if (t < w) red[t] = fmaxf(red[t], red[t + w]); __syncthreads(); }
    mx = red[0];
    __syncthreads();
    float se = (t < NPG) ? expf(ss[t] - mx) : 0.f;
    red[t] = se;
    __syncthreads();
    for (int w = 512; w > 0; w >>= 1) { if (t < w) red[t] += red[t + w]; __syncthreads(); }
    float lse = logf(red[0]);
    __syncthreads();
    const float ln_npg = 6.9077552790f;
    float kl = 0.f;
    if (t < NPG) {
        float lp = ss[t] - mx - lse;
        kl = expf(lp) * (lp + ln_npg);
    }
    red[t] = kl;
    __syncthreads();
    for (int w = 512; w > 0; w >>= 1) { if (t < w) red[t] += red[t + w]; __syncthreads(); }
    if (t == 0) o_kl[g] = red[0];
    unsigned long long v;
    if (t < NPG) {
        unsigned u = __float_as_uint(ss[t]);
        u = (u & 0x80000000u) ? ~u : (u | 0x80000000u);
        v = ((unsigned long long)(~u) << 32) | (unsigned)t;
    } else {
        v = ~0ULL;
    }
    __syncthreads();
    kk[t] = v;
    __syncthreads();
    for (int k = 2; k <= 1024; k <<= 1) {
        for (int j = k >> 1; j > 0; j >>= 1) {
            int ixj = t ^ j;
            if (ixj > t) {
                unsigned long long a = kk[t], b2 = kk[ixj];
                bool up = ((t & k) == 0);
                if ((a > b2) == up) { kk[t] = b2; kk[ixj] = a; }
            }
            __syncthreads();
        }
    }
    if (t < NPG) {
        int idx = (int)(kk[t] & 0xFFFFFFFFULL);
        o_ind[(size_t)g * NPG + t] = (float)idx;
        map[t] = -1;
    }
    __syncthreads();
    if (t < KTOP) {
        int node = (int)(kk[t] & 0xFFFFFFFFULL);
        map[node] = g * KTOP + t;
        o_perm[(size_t)g * KTOP + t] = (float)(gbase + node);
        o_batch[(size_t)g * KTOP + t] = (float)g;
    }
    __syncthreads();
    if (t < NPG) mapping[gbase + t] = map[t];
    for (int r = wave; r < KTOP; r += 16) {
        int node = (int)(kk[r] & 0xFFFFFFFFULL);
        float tn = tanhf(ss[node]);
        o_xnew[((size_t)g * KTOP + r) * C + lane] =
            out2[(size_t)(gbase + node) * C + lane] * tn;
    }
}

// ---------------- edge re-index + mask + attr (device-wide, x4 vectorized) ----------------
__global__ void edge_out_k(const int* __restrict__ ei, const float* __restrict__ eattr,
                           const int* __restrict__ mapping, float* __restrict__ o_newei,
                           float* __restrict__ o_eattr, float* __restrict__ o_mask, int E) {
    int e4 = blockIdx.x * 256 + threadIdx.x;
    int q = E >> 2;
    if (e4 < q) {
        int4 sidx = ((const int4*)ei)[e4];
        int4 didx = ((const int4*)ei)[q + e4];
        int a0 = mapping[sidx.x], a1 = mapping[sidx.y], a2 = mapping[sidx.z], a3 = mapping[sidx.w];
        int b0 = mapping[didx.x], b1 = mapping[didx.y], b2 = mapping[didx.z], b3 = mapping[didx.w];
        float4 f0 = { (float)a0, (float)a1, (float)a2, (float)a3 };
        float4 f1 = { (float)b0, (float)b1, (float)b2, (float)b3 };
        ((float4*)o_newei)[e4] = f0;
        ((float4*)o_newei)[q + e4] = f1;
        float4 at = ((const float4*)eattr)[e4];
        float4 mk, ea;
        mk.x = (a0 >= 0 && b0 >= 0) ? 1.0f : 0.0f;
        mk.y = (a1 >= 0 && b1 >= 0) ? 1.0f : 0.0f;
        mk.z = (a2 >= 0 && b2 >= 0) ? 1.0f : 0.0f;
        mk.w = (a3 >= 0 && b3 >= 0) ? 1.0f : 0.0f;
        ea.x = mk.x != 0.0f ? at.x : 0.0f;
        ea.y = mk.y != 0.0f ? at.y : 0.0f;
        ea.z = mk.z != 0.0f ? at.z : 0.0f;
        ea.w = mk.w != 0.0f ? at.w : 0.0f;
        ((float4*)o_mask)[e4] = mk;
        ((float4*)o_eattr)[e4] = ea;
    }
}

extern "C" void kernel_launch(void* const* d_in, const int* in_sizes, int n_in,
                              void* d_out, int out_size, void* d_ws, size_t ws_size,
                              hipStream_t stream) {
    (void)n_in; (void)out_size; (void)ws_size;
    const float* x     = (const float*)d_in[1];
    const int*   ei    = (const int*)d_in[2];
    const float* eattr = (const float*)d_in[3];
    const float* W     = (const float*)d_in[5];
    const float* bias  = (const float*)d_in[6];

    const int N  = in_sizes[1] / C;    // 256000
    const int E  = in_sizes[2] / 2;    // 4096000
    const int B  = N / NPG;            // 256
    const int BK = B * KTOP;           // 128000

    // workspace layout
    char* wsp = (char*)d_ws;
    float* out2    = (float*)wsp; wsp += (size_t)N * C * 4;   // 65.5 MB
    float* dinv    = (float*)wsp; wsp += (size_t)N * 4;
    int*   deg     = (int*)wsp;   wsp += (size_t)N * 4;
    int*   off     = (int*)wsp;   wsp += (size_t)N * 4;
    int*   mapping = (int*)wsp;   wsp += (size_t)N * 4;
    float* score   = (float*)wsp; wsp += (size_t)N * 4;
    float* cen_sum = (float*)wsp; wsp += (size_t)B * C * 4;

    // output layout (flat f32, reference return order)
    float* out     = (float*)d_out;
    float* o_xnew  = out;                                   // BK*C
    float* o_newei = o_xnew + (size_t)BK * C;               // 2E
    float* o_eattr = o_newei + 2 * (size_t)E;               // E
    float* o_mask  = o_eattr + (size_t)E;                   // E
    float* o_batch = o_mask + (size_t)E;                    // BK
    float* o_perm  = o_batch + (size_t)BK;                  // BK
    float* o_kl    = o_perm + (size_t)BK;                   // B
    float* o_ind   = o_kl + (size_t)B;                      // B*NPG

    // scratch aliased onto d_out (dead before those outputs are written)
    float* h2buf = out;                // N*C floats
    int*   csr   = (int*)o_eattr;      // E ints

    build_graph_k<<<B, 1024, 0, stream>>>(ei, E, deg, dinv, off, csr, cen_sum);
    gemm_k<<<N / 128, 128, 0, stream>>>(x, W, dinv, h2buf, N);
    gather_k<<<B * BPG, 256, 0, stream>>>(csr, off, deg, h2buf, dinv, bias, out2,
                                          cen_sum, N, B);
    score2_k<<<(N + 15) / 16, 256, 0, stream>>>(out2, cen_sum, score, N);
    post2_k<<<B, 1024, 0, stream>>>(score, out2, mapping,
                                    o_xnew, o_batch, o_perm, o_kl, o_ind);
    edge_out_k<<<(E / 4 + 255) / 256, 256, 0, stream>>>(ei, eattr, mapping,
                                                        o_newei, o_eattr, o_mask, E);
}